// Round 20
// baseline (390.734 us; speedup 1.0000x reference)
//
#include <hip/hip_runtime.h>
#include <stdint.h>

// EncoderLayer on MI355X (gfx950), bf16 MFMA pipeline.
// B=4, S=2048, HID=1024, HEADS=16, HD=64, PF=4096. M = B*S = 8192.

typedef __bf16 bf16;
typedef __bf16 bf16x4 __attribute__((ext_vector_type(4)));
typedef __bf16 bf16x8 __attribute__((ext_vector_type(8)));
typedef float  f32x4  __attribute__((ext_vector_type(4)));

__device__ __forceinline__ bf16 f2b(float x){
  uint32_t u = __builtin_bit_cast(uint32_t, x);
  uint32_t r = (u + 0x7FFFu + ((u >> 16) & 1u)) >> 16;   // RNE
  return __builtin_bit_cast(bf16, (uint16_t)r);
}

__device__ __forceinline__ float ex2(float x){
#if __has_builtin(__builtin_amdgcn_exp2f)
  return __builtin_amdgcn_exp2f(x);
#else
  return __exp2f(x);
#endif
}

// async global->LDS, 16B per lane (LDS dest = wave-uniform base + lane*16,
// global source is per-lane)
__device__ __forceinline__ void gload_lds16(const void* g, void* l){
  __builtin_amdgcn_global_load_lds(
      (const __attribute__((address_space(1))) void*)g,
      (__attribute__((address_space(3))) void*)l, 16, 0, 0);
}

// ---------------- prep: src cast + all 6 weight transposes, one launch ------
__global__ __launch_bounds__(256) void prep_kernel(
    const float* __restrict__ src, bf16* __restrict__ srcb,
    const float* __restrict__ Wq, const float* __restrict__ Wk,
    const float* __restrict__ Wv, const float* __restrict__ Wo,
    const float* __restrict__ W1, const float* __restrict__ W2,
    bf16* __restrict__ Wqkvt, bf16* __restrict__ Wot,
    bf16* __restrict__ W1t,  bf16* __restrict__ W2t)
{
  __shared__ float t[32][33];
  const int bb = blockIdx.x, tid = threadIdx.x;
  if (bb < 8192){
    const int i = bb*256 + tid;
    const float4 v = ((const float4*)src)[i];
    bf16x4 u = { f2b(v.x), f2b(v.y), f2b(v.z), f2b(v.w) };
    *(bf16x4*)(srcb + (size_t)i*4) = u;
    return;
  }
  const int idx = bb - 8192;
  const float* W; bf16* Wt; int K, N, bx, by;
  if (idx < 3072){
    const int r = idx >> 10, j = idx & 1023;
    W = (r==0)?Wq:(r==1)?Wk:Wv; Wt = Wqkvt + (size_t)r*1024*1024;
    K = 1024; N = 1024; bx = j & 31; by = j >> 5;
  } else if (idx < 4096){
    const int j = idx - 3072;
    W = Wo; Wt = Wot; K = 1024; N = 1024; bx = j & 31; by = j >> 5;
  } else if (idx < 8192){
    const int j = idx - 4096;
    W = W1; Wt = W1t; K = 1024; N = 4096; bx = j & 127; by = j >> 7;
  } else {
    const int j = idx - 8192;
    W = W2; Wt = W2t; K = 4096; N = 1024; bx = j & 31; by = j >> 5;
  }
  const int x = tid & 31, y = tid >> 5;
  const int n0 = bx*32, k0 = by*32;
  #pragma unroll
  for (int r=0;r<4;r++) t[y+8*r][x] = W[(size_t)(k0+y+8*r)*N + n0+x];
  __syncthreads();
  #pragma unroll
  for (int r=0;r<4;r++) Wt[(size_t)(n0+y+8*r)*K + k0+x] = f2b(t[x][y+8*r]);
}

// ---------------- GEMM 128x128, BK=64, 2-buf single-barrier pipeline --------
// (unchanged from round 19 -- measured best)
template<int OMODE, int REMAP>
__global__ __launch_bounds__(256) void gemm_bt_kernel(
    const bf16* __restrict__ A, const bf16* __restrict__ Bt,
    const float* __restrict__ bias, void* __restrict__ C,
    int M, int N, int K, float oscale,
    const float* __restrict__ bias2, const float* __restrict__ bias3,
    void* __restrict__ C2, void* __restrict__ C3)
{
  __shared__ bf16 As[2][128*64];
  __shared__ bf16 Bs[2][128*64];
  const int tid = threadIdx.x;
  const int w = tid >> 6, lane = tid & 63;
  const int wr = w >> 1, wc = w & 1;
  const int g16 = lane >> 4, l16 = lane & 15;

  const int nbx = N >> 7;
  const int nby = M >> 7;
  const int lin = blockIdx.x;
  int bx, by;
  if constexpr (REMAP==1){
    const int xcd = lin & 7;
    const int j   = lin >> 3;
    by = xcd * (nby >> 3) + (j / nbx);
    bx = j % nbx;
  } else {
    bx = lin % nbx;
    by = lin / nbx;
  }
  const int m0 = by*128, n0 = bx*128;

  const int srow  = tid >> 3;
  const int sslot = ((tid & 7) ^ (srow & 7)) * 8;
  const bf16* gA = A  + (size_t)(m0 + srow)*K + sslot;
  const bf16* gB = Bt + (size_t)(n0 + srow)*K + sslot;

  f32x4 acc[4][4];
  const f32x4 fz = {0.f,0.f,0.f,0.f};
  #pragma unroll
  for (int m=0;m<4;m++)
    #pragma unroll
    for (int n=0;n<4;n++) acc[m][n] = fz;

  bf16x8 ra[4], rb[4];
  #pragma unroll
  for (int k=0;k<4;k++){
    ra[k] = *(const bf16x8*)(gA + (size_t)(32*k)*K);
    rb[k] = *(const bf16x8*)(gB + (size_t)(32*k)*K);
  }
  asm volatile("s_waitcnt vmcnt(0)" ::: "memory");
  #pragma unroll
  for (int k=0;k<4;k++){
    *(bf16x8*)&As[0][(tid + 256*k)*8] = ra[k];
    *(bf16x8*)&Bs[0][(tid + 256*k)*8] = rb[k];
  }
  const int NT = K >> 6;
  if (NT > 1){
    #pragma unroll
    for (int k=0;k<4;k++){
      ra[k] = *(const bf16x8*)(gA + (size_t)(32*k)*K + 64);
      rb[k] = *(const bf16x8*)(gB + (size_t)(32*k)*K + 64);
    }
  }

  const int l7 = l16 & 7;
  for (int t = 0; t < NT; ++t){
    asm volatile("s_waitcnt lgkmcnt(0)" ::: "memory");
    __builtin_amdgcn_s_barrier();
    asm volatile("" ::: "memory");

    const bf16* as = &As[t&1][0];
    const bf16* bs = &Bs[t&1][0];
    bf16x8 af[2][4], bfv[2][4];
    #pragma unroll
    for (int kk=0;kk<2;kk++){
      #pragma unroll
      for (int m=0;m<4;m++){
        const int r = wr*64 + m*16 + l16;
        af[kk][m] = *(const bf16x8*)&as[r*64 + ((((kk<<2)+g16) ^ l7)<<3)];
      }
      #pragma unroll
      for (int n=0;n<4;n++){
        const int r = wc*64 + n*16 + l16;
        bfv[kk][n] = *(const bf16x8*)&bs[r*64 + ((((kk<<2)+g16) ^ l7)<<3)];
      }
    }
    if (t+1 < NT){
      asm volatile("s_waitcnt vmcnt(0)" ::: "memory");
      bf16* aw = &As[(t+1)&1][0];
      bf16* bw = &Bs[(t+1)&1][0];
      #pragma unroll
      for (int k=0;k<4;k++){
        *(bf16x8*)&aw[(tid + 256*k)*8] = ra[k];
        *(bf16x8*)&bw[(tid + 256*k)*8] = rb[k];
      }
      if (t+2 < NT){
        #pragma unroll
        for (int k=0;k<4;k++){
          ra[k] = *(const bf16x8*)(gA + (size_t)(32*k)*K + (t+2)*64);
          rb[k] = *(const bf16x8*)(gB + (size_t)(32*k)*K + (t+2)*64);
        }
      }
    }
    #pragma unroll
    for (int kk=0;kk<2;kk++)
      #pragma unroll
      for (int m=0;m<4;m++)
        #pragma unroll
        for (int n=0;n<4;n++)
          acc[m][n] = __builtin_amdgcn_mfma_f32_16x16x32_bf16(
              af[kk][m], bfv[kk][n], acc[m][n], 0, 0, 0);
  }

  // epilogue: D[i][j]: j = lane&15, i = 4*(lane>>4)+reg  [measured layout]
  const int cb = n0 + wc*64 + l16;
  if constexpr (OMODE==4){
    const int region = n0 >> 10;
    const float* bs2 = (region==0)? bias : (region==1)? bias2 : bias3;
    const int colbase = region << 10;
    #pragma unroll
    for (int n=0;n<4;n++){
      const int cl = cb + n*16 - colbase;
      const float bv = bs2[cl];
      #pragma unroll
      for (int m=0;m<4;m++){
        const int rbase = m0 + wr*64 + m*16 + g16*4;
        if (region==2){
          const size_t bq = (size_t)rbase >> 11;
          const int s  = rbase & 2047;
          const int s6 = s & 63;
          const int sp = (s & ~63) | (s6 & 32) | ((s6 & 12) << 1)
                       | ((s6 & 16) >> 2);
          bf16x4 v4 = { f2b(acc[m][n][0] + bv), f2b(acc[m][n][1] + bv),
                        f2b(acc[m][n][2] + bv), f2b(acc[m][n][3] + bv) };
          *(bf16x4*)&((bf16*)C3)[(bq*1024 + (size_t)cl)*2048 + sp] = v4;
        } else {
          #pragma unroll
          for (int r=0;r<4;r++){
            const float v = acc[m][n][r] + bv;
            const size_t row = (size_t)(rbase + r);
            if (region==0) ((bf16*)C )[row*1024 + cl] = f2b(v * oscale);
            else           ((bf16*)C2)[row*1024 + cl] = f2b(v);
          }
        }
      }
    }
  } else {
    #pragma unroll
    for (int n=0;n<4;n++){
      const int col = cb + n*16;
      const float bv = bias[col];
      #pragma unroll
      for (int m=0;m<4;m++){
        const int rbase = m0 + wr*64 + m*16 + g16*4;
        #pragma unroll
        for (int r=0;r<4;r++){
          float v = acc[m][n][r] + bv;
          const size_t row = (size_t)(rbase + r);
          if constexpr (OMODE==0){
            ((float*)C)[row*N + col] = v;
          } else if constexpr (OMODE==1){
            ((bf16*)C)[row*N + col] = f2b(v * oscale);
          } else {
            v = v / (1.f + __expf(-v));
            ((bf16*)C)[row*N + col] = f2b(v);
          }
        }
      }
    }
  }
}

// ---------------- flash attention (64 q/wave: halved LDS-read traffic) -----
// grid 512 blocks, XCD-aware (b,h) clustering. 4 waves/block (256 thr),
// wave = 64 q (4 q-groups of 16). KV tile 64, THREE LDS bufs (49KB ->
// 2 blocks/CU). Same depth-2 drift schedule as round 19; per-q arithmetic
// identical (only the wave->q mapping changed), so output is bit-identical.
// Halving waves per staged tile halves the redundant K/V ds_read_b128
// traffic per q-row (all waves read the same LDS addresses).
__global__ __launch_bounds__(256) void attn_kernel(
    const bf16* __restrict__ Q, const bf16* __restrict__ Km,
    const bf16* __restrict__ Vt, const int* __restrict__ msk,
    bf16* __restrict__ O)
{
  __shared__ bf16 Ks[3][64*64];
  __shared__ bf16 Vs[3][64*64];
  __shared__ int  Mflag[32];

  const int tid = threadIdx.x;
  const int w = tid>>6, lane = tid&63;          // w = 0..3
  const int g16 = lane>>4, l16 = lane&15;
  const int lin = blockIdx.x;                   // 0..511
  const int xcd = lin & 7, idx = lin >> 3;      // XCD = blockIdx % 8
  const int bh  = xcd*8 + (idx >> 3);           // 8 (b,h) groups per XCD
  const int qt  = idx & 7;                      // 8 q-tiles of 256
  const int b = bh >> 4, h = bh & 15;
  const int q0 = qt*256 + w*64;                 // 64 q per wave

  const bf16* Kb = Km + (size_t)b*2048*1024 + h*64;
  const bf16* Vb = Vt + (size_t)(b*16 + h)*64*2048;
  const int*  mb = msk + b*2048;

  if (tid < 32) Mflag[tid] = 1;

  // staging: 4 waves x 16 rows per tile (2 gloads per operand per wave)
  const int srow = w*16 + (lane>>3);
  const int sslot = ((lane&7) ^ (lane>>3)) * 8;
  const bf16* gK0 = Kb + (size_t)srow*1024 + sslot;
  const bf16* gV0 = Vb + (size_t)srow*2048 + sslot;

  auto stage = [&](int buf, int kv0){
    bf16* kl = &Ks[buf][w*1024];
    bf16* vl = &Vs[buf][w*1024];
    gload_lds16(gK0 + (size_t)kv0*1024, kl);
    gload_lds16(gK0 + (size_t)(kv0+8)*1024, kl + 512);
    gload_lds16(gV0 + kv0,      vl);
    gload_lds16(gV0 + kv0 + 8,  vl + 512);
  };

  // Q fragments (B-operand): col=q=l16, k=d=g16*8+e (+32); 4 q-groups
  bf16x8 qf[4][2];
  #pragma unroll
  for (int qg=0;qg<4;qg++){
    const bf16* qp = Q + (size_t)(b*2048 + q0 + qg*16 + l16)*1024 + h*64 + g16*8;
    qf[qg][0] = *(const bf16x8*)qp;
    qf[qg][1] = *(const bf16x8*)(qp + 32);
  }

  __syncthreads();                       // Mflag init visible
  {
    const int4 a = *(const int4*)(mb + tid*8);
    const int4 c = *(const int4*)(mb + tid*8 + 4);
    const bool ok = a.x && a.y && a.z && a.w && c.x && c.y && c.z && c.w;
    if (!ok) atomicAnd(&Mflag[tid>>3], 0);
  }
  stage(0, 0);
  stage(1, 64);
  __syncthreads();                       // flags final + stage(0),(1) landed

  const int l7 = l16 & 7;
  const int kOff0 = l16*64 + ((g16     ^ l7) << 3);   // also V slot w2=0
  const int kOff1 = l16*64 + (((4+g16) ^ l7) << 3);   // also V slot w2=1

  bf16x8 ones8;
  #pragma unroll
  for (int j=0;j<8;j++) ones8[j] = (bf16)1.0f;

  const f32x4 fz = {0.f,0.f,0.f,0.f};
  f32x4 xa[4][4];
  f32x4 lacc[4] = {fz, fz, fz, fz};
  #pragma unroll
  for (int qg=0;qg<4;qg++)
    #pragma unroll
    for (int jd=0;jd<4;jd++) xa[qg][jd] = fz;

  int cur = 0;
  for (int it = 0; it < 32; ++it){
    const int kv0 = it*64;
    const bf16* ksb = &Ks[cur][0];
    const bf16* vsb = &Vs[cur][0];

    bf16x8 kk[4][2];
    #pragma unroll
    for (int t=0;t<4;t++){
      kk[t][0] = *(const bf16x8*)(ksb + t*1024 + kOff0);
      kk[t][1] = *(const bf16x8*)(ksb + t*1024 + kOff1);
    }
    bf16x8 vw[2][4];
    #pragma unroll
    for (int jd=0;jd<4;jd++){
      vw[0][jd] = *(const bf16x8*)(vsb + jd*1024 + kOff0);
      vw[1][jd] = *(const bf16x8*)(vsb + jd*1024 + kOff1);
    }

    if (it < 30){
      const int pb = (cur >= 1) ? cur-1 : 2;
      stage(pb, kv0 + 128);
    }
    if (it < 30)       asm volatile("s_waitcnt vmcnt(4)" ::: "memory");
    else if (it == 30) asm volatile("s_waitcnt vmcnt(0)" ::: "memory");
    asm volatile("s_waitcnt lgkmcnt(0)" ::: "memory");   // reads consumed
    if (it < 31){
      asm volatile("" ::: "memory");
      __builtin_amdgcn_s_barrier();
      asm volatile("" ::: "memory");
    }

    const bool needmask = !Mflag[it];
    int4 mm[4];
    if (needmask){
      #pragma unroll
      for (int t=0;t<4;t++) mm[t] = *(const int4*)(mb + kv0 + t*16 + 4*g16);
    }

    // per q-group: QK^T -> (mask) -> exp2 -> pack; st liveness limited to 16
    bf16x8 pw[4][2];
    #pragma unroll
    for (int qg=0;qg<4;qg++){
      f32x4 st[4];
      __builtin_amdgcn_s_setprio(1);
      #pragma unroll
      for (int t=0;t<4;t++){
        f32x4 a = fz;
        a = __builtin_amdgcn_mfma_f32_16x16x32_bf16(kk[t][0], qf[qg][0], a, 0,0,0);
        a = __builtin_amdgcn_mfma_f32_16x16x32_bf16(kk[t][1], qf[qg][1], a, 0,0,0);
        st[t] = a;
      }
      __builtin_amdgcn_s_setprio(0);
      if (needmask){
        #pragma unroll
        for (int t=0;t<4;t++){
          st[t][0] = (mm[t].x==0) ? -1e9f : st[t][0];
          st[t][1] = (mm[t].y==0) ? -1e9f : st[t][1];
          st[t][2] = (mm[t].z==0) ? -1e9f : st[t][2];
          st[t][3] = (mm[t].w==0) ? -1e9f : st[t][3];
        }
      }
      #pragma unroll
      for (int t=0;t<4;t++){
        const int hb = (t&1)*4;
        pw[qg][t>>1][hb+0] = (bf16)ex2(st[t][0]);
        pw[qg][t>>1][hb+1] = (bf16)ex2(st[t][1]);
        pw[qg][t>>1][hb+2] = (bf16)ex2(st[t][2]);
        pw[qg][t>>1][hb+3] = (bf16)ex2(st[t][3]);
      }
    }
    // PV + row-sum (A=ones)
    __builtin_amdgcn_s_setprio(1);
    #pragma unroll
    for (int w2=0;w2<2;w2++){
      #pragma unroll
      for (int qg=0;qg<4;qg++){
        #pragma unroll
        for (int jd=0;jd<4;jd++)
          xa[qg][jd] = __builtin_amdgcn_mfma_f32_16x16x32_bf16(vw[w2][jd], pw[qg][w2], xa[qg][jd], 0,0,0);
        lacc[qg] = __builtin_amdgcn_mfma_f32_16x16x32_bf16(ones8, pw[qg][w2], lacc[qg], 0,0,0);
      }
    }
    __builtin_amdgcn_s_setprio(0);

    cur = (cur==2) ? 0 : cur+1;
  }

  // write O: lane holds q=l16 (per group), d = jd*16 + 4*g16 + r
  #pragma unroll
  for (int qg=0;qg<4;qg++){
    const float rl = 1.f / lacc[qg][0];
    const size_t row = (size_t)(b*2048 + q0 + qg*16 + l16);
    #pragma unroll
    for (int jd=0;jd<4;jd++){
      bf16x4 ov = { f2b(xa[qg][jd][0]*rl), f2b(xa[qg][jd][1]*rl),
                    f2b(xa[qg][jd][2]*rl), f2b(xa[qg][jd][3]*rl) };
      *(bf16x4*)(O + row*1024 + h*64 + jd*16 + 4*g16) = ov;
    }
  }
}

// ---------------- residual + layernorm (row = 1024) ----------------
// X in bf16; residual R is f32 (RBF=0) or bf16 (RBF=1).
template<int RBF>
__global__ __launch_bounds__(256) void addln_kernel(
    const bf16* __restrict__ X, const void* __restrict__ R,
    const float* __restrict__ g, const float* __restrict__ be,
    float* __restrict__ of, bf16* __restrict__ ob)
{
  const int row = blockIdx.x, tid = threadIdx.x;
  const bf16x4 vxb = *(const bf16x4*)(X + (size_t)row*1024 + tid*4);
  float r0, r1, r2, r3;
  if constexpr (RBF==1){
    const bf16x4 vrb = *(const bf16x4*)((const bf16*)R + (size_t)row*1024 + tid*4);
    r0 = (float)vrb[0]; r1 = (float)vrb[1]; r2 = (float)vrb[2]; r3 = (float)vrb[3];
  } else {
    const float4 vr = ((const float4*)((const float*)R + (size_t)row*1024))[tid];
    r0 = vr.x; r1 = vr.y; r2 = vr.z; r3 = vr.w;
  }
  const float a0 = (float)vxb[0]+r0, a1 = (float)vxb[1]+r1;
  const float a2 = (float)vxb[2]+r2, a3 = (float)vxb[3]+r3;
  float s = a0+a1+a2+a3;
  float q = a0*a0 + a1*a1 + a2*a2 + a3*a3;
  #pragma unroll
  for (int off=1; off<64; off<<=1){
    s += __shfl_xor(s, off, 64);
    q += __shfl_xor(q, off, 64);
  }
  __shared__ float sb[8];
  if ((tid&63)==0){ sb[tid>>6] = s; sb[4+(tid>>6)] = q; }
  __syncthreads();
  s = sb[0]+sb[1]+sb[2]+sb[3];
  q = sb[4]+sb[5]+sb[6]+sb[7];
  const float mu = s*(1.f/1024.f);
  const float rs = rsqrtf(q*(1.f/1024.f) - mu*mu + 1e-5f);
  const float4 gg = ((const float4*)g)[tid];
  const float4 bb = ((const float4*)be)[tid];
  const float o0 = (a0-mu)*rs*gg.x + bb.x;
  const float o1 = (a1-mu)*rs*gg.y + bb.y;
  const float o2 = (a2-mu)*rs*gg.z + bb.z;
  const float o3 = (a3-mu)*rs*gg.w + bb.w;
  if (of){
    float4 o; o.x=o0; o.y=o1; o.z=o2; o.w=o3;
    ((float4*)(of + (size_t)row*1024))[tid] = o;
  }
  if (ob){
    bf16x4 u = { f2b(o0), f2b(o1), f2b(o2), f2b(o3) };
    *(bf16x4*)(ob + (size_t)row*1024 + tid*4) = u;
  }
}

// ---------------- launch ----------------
extern "C" void kernel_launch(void* const* d_in, const int* in_sizes, int n_in,
                              void* d_out, int out_size, void* d_ws, size_t ws_size,
                              hipStream_t stream)
{
  const float* src  = (const float*)d_in[0];
  const int*   mask = (const int*)  d_in[1];
  const float* Wq = (const float*)d_in[2];  const float* bq = (const float*)d_in[3];
  const float* Wk = (const float*)d_in[4];  const float* bk = (const float*)d_in[5];
  const float* Wv = (const float*)d_in[6];  const float* bv = (const float*)d_in[7];
  const float* Wo = (const float*)d_in[8];  const float* bo = (const float*)d_in[9];
  const float* W1 = (const float*)d_in[10]; const float* b1 = (const float*)d_in[11];
  const float* W2 = (const float*)d_in[12]; const float* b2 = (const float*)d_in[13];
  const float* g1 = (const float*)d_in[14]; const float* be1 = (const float*)d_in[15];
  const float* g2 = (const float*)d_in[16]; const float* be2 = (const float*)d_in[17];

  char* ws = (char*)d_ws;
  const size_t MB = 1u<<20;
  bf16* srcb  = (bf16*)(ws + 0*MB);    // 16 MB  [dead after QKV gemm]
  bf16* Wqkvt = (bf16*)(ws + 16*MB);   // 6 MB
  bf16* Wot   = (bf16*)(ws + 22*MB);   // 2 MB
  bf16* W1t   = (bf16*)(ws + 24*MB);   // 8 MB
  bf16* W2t   = (bf16*)(ws + 32*MB);   // 8 MB
  bf16* Qb    = (bf16*)(ws + 40*MB);   // 16 MB [dead after attn]
  bf16* Kb    = (bf16*)(ws + 56*MB);   // 16 MB [dead after attn]
  bf16* Vtb   = (bf16*)(ws + 72*MB);   // 16 MB [dead after attn]
  bf16* AO    = (bf16*)(ws + 88*MB);   // 16 MB [dead after O-proj]
  bf16*  X1   = (bf16*)(ws + 40*MB);   // 16 MB over Qb (bf16)
  bf16*  S1B  = (bf16*)(ws + 72*MB);   // 16 MB over Vtb (LN1 out, bf16 only)
  bf16*  H1   = (bf16*)(ws + 104*MB);  // 64 MB
  bf16*  F2   = (bf16*)(ws + 40*MB);   // 16 MB over X1 (dead after LN1)

  const float QSC = 0.18033688011112042f;   // 0.125 * log2(e)

  prep_kernel<<<20480, 256, 0, stream>>>(src, srcb, Wq, Wk, Wv, Wo, W1, W2,
                                         Wqkvt, Wot, W1t, W2t);

  // fused QKV projection (N=3072): wide-N -> plain bx-fastest order
  gemm_bt_kernel<4,0><<<24*64, 256, 0, stream>>>(
      srcb, Wqkvt, bq, Qb, 8192, 3072, 1024, QSC, bk, bv, Kb, Vtb);

  attn_kernel<<<512, 256, 0, stream>>>(Qb, Kb, Vtb, mask, AO);

  // O-proj (N=1024): narrow-N -> XCD row-panel ownership
  gemm_bt_kernel<1,1><<<8*64,  256, 0, stream>>>(
      AO, Wot, bo, X1, 8192, 1024, 1024, 1.f, nullptr, nullptr, nullptr, nullptr);
  // LN1: residual = src (f32); bf16 output only
  addln_kernel<0><<<8192, 256, 0, stream>>>(X1, src, g1, be1,
                                            (float*)nullptr, S1B);

  // FFN1 (N=4096, swish): wide-N -> plain order ; FFN2 (N=1024): XCD-remap
  gemm_bt_kernel<2,0><<<32*64, 256, 0, stream>>>(
      S1B, W1t, b1, H1, 8192, 4096, 1024, 1.f, nullptr, nullptr, nullptr, nullptr);
  gemm_bt_kernel<1,1><<<8*64,  256, 0, stream>>>(
      H1,  W2t, b2, F2, 8192, 1024, 4096, 1.f, nullptr, nullptr, nullptr, nullptr);
  // LN2: residual = S1B (bf16); f32 output to d_out
  addln_kernel<1><<<8192, 256, 0, stream>>>(F2, S1B, g2, be2,
                                            (float*)d_out, (bf16*)nullptr);
}

// Round 21
// 369.244 us; speedup vs baseline: 1.0582x; 1.0582x over previous
//
#include <hip/hip_runtime.h>
#include <stdint.h>

// EncoderLayer on MI355X (gfx950), bf16 MFMA pipeline.
// B=4, S=2048, HID=1024, HEADS=16, HD=64, PF=4096. M = B*S = 8192.

typedef __bf16 bf16;
typedef __bf16 bf16x4 __attribute__((ext_vector_type(4)));
typedef __bf16 bf16x8 __attribute__((ext_vector_type(8)));
typedef float  f32x4  __attribute__((ext_vector_type(4)));

__device__ __forceinline__ bf16 f2b(float x){
  uint32_t u = __builtin_bit_cast(uint32_t, x);
  uint32_t r = (u + 0x7FFFu + ((u >> 16) & 1u)) >> 16;   // RNE
  return __builtin_bit_cast(bf16, (uint16_t)r);
}

__device__ __forceinline__ float ex2(float x){
#if __has_builtin(__builtin_amdgcn_exp2f)
  return __builtin_amdgcn_exp2f(x);
#else
  return __exp2f(x);
#endif
}

// async global->LDS, 16B per lane (LDS dest = wave-uniform base + lane*16,
// global source is per-lane)
__device__ __forceinline__ void gload_lds16(const void* g, void* l){
  __builtin_amdgcn_global_load_lds(
      (const __attribute__((address_space(1))) void*)g,
      (__attribute__((address_space(3))) void*)l, 16, 0, 0);
}

// ---------------- prep: src cast + all 6 weight transposes, one launch ------
__global__ __launch_bounds__(256) void prep_kernel(
    const float* __restrict__ src, bf16* __restrict__ srcb,
    const float* __restrict__ Wq, const float* __restrict__ Wk,
    const float* __restrict__ Wv, const float* __restrict__ Wo,
    const float* __restrict__ W1, const float* __restrict__ W2,
    bf16* __restrict__ Wqkvt, bf16* __restrict__ Wot,
    bf16* __restrict__ W1t,  bf16* __restrict__ W2t)
{
  __shared__ float t[32][33];
  const int bb = blockIdx.x, tid = threadIdx.x;
  if (bb < 8192){
    const int i = bb*256 + tid;
    const float4 v = ((const float4*)src)[i];
    bf16x4 u = { f2b(v.x), f2b(v.y), f2b(v.z), f2b(v.w) };
    *(bf16x4*)(srcb + (size_t)i*4) = u;
    return;
  }
  const int idx = bb - 8192;
  const float* W; bf16* Wt; int K, N, bx, by;
  if (idx < 3072){
    const int r = idx >> 10, j = idx & 1023;
    W = (r==0)?Wq:(r==1)?Wk:Wv; Wt = Wqkvt + (size_t)r*1024*1024;
    K = 1024; N = 1024; bx = j & 31; by = j >> 5;
  } else if (idx < 4096){
    const int j = idx - 3072;
    W = Wo; Wt = Wot; K = 1024; N = 1024; bx = j & 31; by = j >> 5;
  } else if (idx < 8192){
    const int j = idx - 4096;
    W = W1; Wt = W1t; K = 1024; N = 4096; bx = j & 127; by = j >> 7;
  } else {
    const int j = idx - 8192;
    W = W2; Wt = W2t; K = 4096; N = 1024; bx = j & 31; by = j >> 5;
  }
  const int x = tid & 31, y = tid >> 5;
  const int n0 = bx*32, k0 = by*32;
  #pragma unroll
  for (int r=0;r<4;r++) t[y+8*r][x] = W[(size_t)(k0+y+8*r)*N + n0+x];
  __syncthreads();
  #pragma unroll
  for (int r=0;r<4;r++) Wt[(size_t)(n0+y+8*r)*K + k0+x] = f2b(t[x][y+8*r]);
}

// ---------------- GEMM 128x128, BK=64, 2-buf single-barrier pipeline --------
// C = A[M][K] * Bt[N][K]^T + bias. 4 waves (2x2), wave = 64x64 = 4x4 frags of
// 16x16x32. Reg-staged prefetch, TWO LDS buffers (64 KB -> 2 blocks/CU),
// ONE barrier per 64-K step.
template<int OMODE, int REMAP>
__global__ __launch_bounds__(256) void gemm_bt_kernel(
    const bf16* __restrict__ A, const bf16* __restrict__ Bt,
    const float* __restrict__ bias, void* __restrict__ C,
    int M, int N, int K, float oscale,
    const float* __restrict__ bias2, const float* __restrict__ bias3,
    void* __restrict__ C2, void* __restrict__ C3)
{
  __shared__ bf16 As[2][128*64];
  __shared__ bf16 Bs[2][128*64];
  const int tid = threadIdx.x;
  const int w = tid >> 6, lane = tid & 63;
  const int wr = w >> 1, wc = w & 1;
  const int g16 = lane >> 4, l16 = lane & 15;

  const int nbx = N >> 7;
  const int nby = M >> 7;
  const int lin = blockIdx.x;
  int bx, by;
  if constexpr (REMAP==1){
    const int xcd = lin & 7;
    const int j   = lin >> 3;
    by = xcd * (nby >> 3) + (j / nbx);
    bx = j % nbx;
  } else {
    bx = lin % nbx;
    by = lin / nbx;
  }
  const int m0 = by*128, n0 = bx*128;

  const int srow  = tid >> 3;
  const int sslot = ((tid & 7) ^ (srow & 7)) * 8;
  const bf16* gA = A  + (size_t)(m0 + srow)*K + sslot;
  const bf16* gB = Bt + (size_t)(n0 + srow)*K + sslot;

  f32x4 acc[4][4];
  const f32x4 fz = {0.f,0.f,0.f,0.f};
  #pragma unroll
  for (int m=0;m<4;m++)
    #pragma unroll
    for (int n=0;n<4;n++) acc[m][n] = fz;

  bf16x8 ra[4], rb[4];
  #pragma unroll
  for (int k=0;k<4;k++){
    ra[k] = *(const bf16x8*)(gA + (size_t)(32*k)*K);
    rb[k] = *(const bf16x8*)(gB + (size_t)(32*k)*K);
  }
  asm volatile("s_waitcnt vmcnt(0)" ::: "memory");
  #pragma unroll
  for (int k=0;k<4;k++){
    *(bf16x8*)&As[0][(tid + 256*k)*8] = ra[k];
    *(bf16x8*)&Bs[0][(tid + 256*k)*8] = rb[k];
  }
  const int NT = K >> 6;
  if (NT > 1){
    #pragma unroll
    for (int k=0;k<4;k++){
      ra[k] = *(const bf16x8*)(gA + (size_t)(32*k)*K + 64);
      rb[k] = *(const bf16x8*)(gB + (size_t)(32*k)*K + 64);
    }
  }

  const int l7 = l16 & 7;
  for (int t = 0; t < NT; ++t){
    asm volatile("s_waitcnt lgkmcnt(0)" ::: "memory");
    __builtin_amdgcn_s_barrier();
    asm volatile("" ::: "memory");

    const bf16* as = &As[t&1][0];
    const bf16* bs = &Bs[t&1][0];
    bf16x8 af[2][4], bfv[2][4];
    #pragma unroll
    for (int kk=0;kk<2;kk++){
      #pragma unroll
      for (int m=0;m<4;m++){
        const int r = wr*64 + m*16 + l16;
        af[kk][m] = *(const bf16x8*)&as[r*64 + ((((kk<<2)+g16) ^ l7)<<3)];
      }
      #pragma unroll
      for (int n=0;n<4;n++){
        const int r = wc*64 + n*16 + l16;
        bfv[kk][n] = *(const bf16x8*)&bs[r*64 + ((((kk<<2)+g16) ^ l7)<<3)];
      }
    }
    if (t+1 < NT){
      asm volatile("s_waitcnt vmcnt(0)" ::: "memory");
      bf16* aw = &As[(t+1)&1][0];
      bf16* bw = &Bs[(t+1)&1][0];
      #pragma unroll
      for (int k=0;k<4;k++){
        *(bf16x8*)&aw[(tid + 256*k)*8] = ra[k];
        *(bf16x8*)&bw[(tid + 256*k)*8] = rb[k];
      }
      if (t+2 < NT){
        #pragma unroll
        for (int k=0;k<4;k++){
          ra[k] = *(const bf16x8*)(gA + (size_t)(32*k)*K + (t+2)*64);
          rb[k] = *(const bf16x8*)(gB + (size_t)(32*k)*K + (t+2)*64);
        }
      }
    }
    #pragma unroll
    for (int kk=0;kk<2;kk++)
      #pragma unroll
      for (int m=0;m<4;m++)
        #pragma unroll
        for (int n=0;n<4;n++)
          acc[m][n] = __builtin_amdgcn_mfma_f32_16x16x32_bf16(
              af[kk][m], bfv[kk][n], acc[m][n], 0, 0, 0);
  }

  // epilogue: D[i][j]: j = lane&15, i = 4*(lane>>4)+reg  [measured layout]
  const int cb = n0 + wc*64 + l16;
  if constexpr (OMODE==4){
    const int region = n0 >> 10;
    const float* bs2 = (region==0)? bias : (region==1)? bias2 : bias3;
    const int colbase = region << 10;
    #pragma unroll
    for (int n=0;n<4;n++){
      const int cl = cb + n*16 - colbase;
      const float bv = bs2[cl];
      #pragma unroll
      for (int m=0;m<4;m++){
        const int rbase = m0 + wr*64 + m*16 + g16*4;
        if (region==2){
          const size_t bq = (size_t)rbase >> 11;
          const int s  = rbase & 2047;
          const int s6 = s & 63;
          const int sp = (s & ~63) | (s6 & 32) | ((s6 & 12) << 1)
                       | ((s6 & 16) >> 2);
          bf16x4 v4 = { f2b(acc[m][n][0] + bv), f2b(acc[m][n][1] + bv),
                        f2b(acc[m][n][2] + bv), f2b(acc[m][n][3] + bv) };
          *(bf16x4*)&((bf16*)C3)[(bq*1024 + (size_t)cl)*2048 + sp] = v4;
        } else {
          #pragma unroll
          for (int r=0;r<4;r++){
            const float v = acc[m][n][r] + bv;
            const size_t row = (size_t)(rbase + r);
            if (region==0) ((bf16*)C )[row*1024 + cl] = f2b(v * oscale);
            else           ((bf16*)C2)[row*1024 + cl] = f2b(v);
          }
        }
      }
    }
  } else {
    #pragma unroll
    for (int n=0;n<4;n++){
      const int col = cb + n*16;
      const float bv = bias[col];
      #pragma unroll
      for (int m=0;m<4;m++){
        const int rbase = m0 + wr*64 + m*16 + g16*4;
        #pragma unroll
        for (int r=0;r<4;r++){
          float v = acc[m][n][r] + bv;
          const size_t row = (size_t)(rbase + r);
          if constexpr (OMODE==0){
            ((float*)C)[row*N + col] = v;
          } else if constexpr (OMODE==1){
            ((bf16*)C)[row*N + col] = f2b(v * oscale);
          } else {
            v = v / (1.f + __expf(-v));
            ((bf16*)C)[row*N + col] = f2b(v);
          }
        }
      }
    }
  }
}

// ---------------- flash attention (depth-2 staging, drift-compute) ---------
// grid 512 blocks, XCD-aware (b,h) clustering. 8 waves/block (512 thr),
// wave = 32 q. KV tile 64, THREE LDS bufs (49KB -> 2 blocks/CU).
// Per tile: ds_read buf[t%3] -> stage(t+2) -> vmcnt(2) -> lgkmcnt(0)
// -> raw s_barrier -> compute (no trailing barrier: waves drift).
// - PV at K=32 via kv->k relabeling; V^T pre-interleaved in global memory.
// - l = sum(P) via MFMAs with A=ones.  - No running max (exp2-domain, safe).
__global__ __launch_bounds__(512) void attn_kernel(
    const bf16* __restrict__ Q, const bf16* __restrict__ Km,
    const bf16* __restrict__ Vt, const int* __restrict__ msk,
    bf16* __restrict__ O)
{
  __shared__ bf16 Ks[3][64*64];
  __shared__ bf16 Vs[3][64*64];
  __shared__ int  Mflag[32];

  const int tid = threadIdx.x;
  const int w = tid>>6, lane = tid&63;          // w = 0..7
  const int g16 = lane>>4, l16 = lane&15;
  const int lin = blockIdx.x;                   // 0..511
  const int xcd = lin & 7, idx = lin >> 3;      // XCD = blockIdx % 8
  const int bh  = xcd*8 + (idx >> 3);           // 8 (b,h) groups per XCD
  const int qt  = idx & 7;                      // 8 q-tiles of 256
  const int b = bh >> 4, h = bh & 15;
  const int q0 = qt*256 + w*32;

  const bf16* Kb = Km + (size_t)b*2048*1024 + h*64;
  const bf16* Vb = Vt + (size_t)(b*16 + h)*64*2048;
  const int*  mb = msk + b*2048;

  if (tid < 32) Mflag[tid] = 1;

  const int srow = w*8 + (lane>>3);
  const int sslot = ((lane&7) ^ (lane>>3)) * 8;
  const bf16* gK0 = Kb + (size_t)srow*1024 + sslot;
  const bf16* gV0 = Vb + (size_t)srow*2048 + sslot;

  auto stage = [&](int buf, int kv0){
    gload_lds16(gK0 + (size_t)kv0*1024, &Ks[buf][w*512]);
    gload_lds16(gV0 + kv0,              &Vs[buf][w*512]);
  };

  // Q fragments (B-operand): col=q=l16, k=d=g16*8+e (+32)
  bf16x8 qf[2][2];
  #pragma unroll
  for (int qg=0;qg<2;qg++){
    const bf16* qp = Q + (size_t)(b*2048 + q0 + qg*16 + l16)*1024 + h*64 + g16*8;
    qf[qg][0] = *(const bf16x8*)qp;
    qf[qg][1] = *(const bf16x8*)(qp + 32);
  }

  __syncthreads();                       // Mflag init visible
  {
    const int4 a = *(const int4*)(mb + tid*4);
    const bool ok = a.x && a.y && a.z && a.w;
    if (!ok) atomicAnd(&Mflag[tid>>4], 0);
  }
  stage(0, 0);
  stage(1, 64);
  __syncthreads();                       // flags final + stage(0),(1) landed

  const int l7 = l16 & 7;
  const int kOff0 = l16*64 + ((g16     ^ l7) << 3);   // also V slot w2=0
  const int kOff1 = l16*64 + (((4+g16) ^ l7) << 3);   // also V slot w2=1

  bf16x8 ones8;
  #pragma unroll
  for (int j=0;j<8;j++) ones8[j] = (bf16)1.0f;

  const f32x4 fz = {0.f,0.f,0.f,0.f};
  f32x4 xa[2][4];
  f32x4 lacc[2] = {fz, fz};
  #pragma unroll
  for (int qg=0;qg<2;qg++)
    #pragma unroll
    for (int jd=0;jd<4;jd++) xa[qg][jd] = fz;

  int cur = 0;
  for (int it = 0; it < 32; ++it){
    const int kv0 = it*64;
    const bf16* ksb = &Ks[cur][0];
    const bf16* vsb = &Vs[cur][0];

    bf16x8 kk[4][2];
    #pragma unroll
    for (int t=0;t<4;t++){
      kk[t][0] = *(const bf16x8*)(ksb + t*1024 + kOff0);
      kk[t][1] = *(const bf16x8*)(ksb + t*1024 + kOff1);
    }
    bf16x8 vw[2][4];
    #pragma unroll
    for (int jd=0;jd<4;jd++){
      vw[0][jd] = *(const bf16x8*)(vsb + jd*1024 + kOff0);
      vw[1][jd] = *(const bf16x8*)(vsb + jd*1024 + kOff1);
    }

    if (it < 30){
      const int pb = (cur >= 1) ? cur-1 : 2;
      stage(pb, kv0 + 128);
    }
    if (it < 30)       asm volatile("s_waitcnt vmcnt(2)" ::: "memory");
    else if (it == 30) asm volatile("s_waitcnt vmcnt(0)" ::: "memory");
    asm volatile("s_waitcnt lgkmcnt(0)" ::: "memory");   // reads consumed
    if (it < 31){
      asm volatile("" ::: "memory");
      __builtin_amdgcn_s_barrier();
      asm volatile("" ::: "memory");
    }

    // ---- compute tile it (no trailing barrier: waves drift) ----
    f32x4 st[2][4];
    __builtin_amdgcn_s_setprio(1);
    #pragma unroll
    for (int qg=0;qg<2;qg++){
      #pragma unroll
      for (int t=0;t<4;t++){
        f32x4 a = fz;
        a = __builtin_amdgcn_mfma_f32_16x16x32_bf16(kk[t][0], qf[qg][0], a, 0,0,0);
        a = __builtin_amdgcn_mfma_f32_16x16x32_bf16(kk[t][1], qf[qg][1], a, 0,0,0);
        st[qg][t] = a;
      }
    }
    __builtin_amdgcn_s_setprio(0);

    if (!Mflag[it]){
      int4 mm[4];
      #pragma unroll
      for (int t=0;t<4;t++) mm[t] = *(const int4*)(mb + kv0 + t*16 + 4*g16);
      #pragma unroll
      for (int qg=0;qg<2;qg++)
        #pragma unroll
        for (int t=0;t<4;t++){
          st[qg][t][0] = (mm[t].x==0) ? -1e9f : st[qg][t][0];
          st[qg][t][1] = (mm[t].y==0) ? -1e9f : st[qg][t][1];
          st[qg][t][2] = (mm[t].z==0) ? -1e9f : st[qg][t][2];
          st[qg][t][3] = (mm[t].w==0) ? -1e9f : st[qg][t][3];
        }
    }

    bf16x8 pw[2][2];
    #pragma unroll
    for (int qg=0;qg<2;qg++){
      #pragma unroll
      for (int t=0;t<4;t++){
        const int hb = (t&1)*4;
        pw[qg][t>>1][hb+0] = (bf16)ex2(st[qg][t][0]);
        pw[qg][t>>1][hb+1] = (bf16)ex2(st[qg][t][1]);
        pw[qg][t>>1][hb+2] = (bf16)ex2(st[qg][t][2]);
        pw[qg][t>>1][hb+3] = (bf16)ex2(st[qg][t][3]);
      }
    }
    __builtin_amdgcn_s_setprio(1);
    #pragma unroll
    for (int w2=0;w2<2;w2++){
      #pragma unroll
      for (int jd=0;jd<4;jd++){
        xa[0][jd] = __builtin_amdgcn_mfma_f32_16x16x32_bf16(vw[w2][jd], pw[0][w2], xa[0][jd], 0,0,0);
        xa[1][jd] = __builtin_amdgcn_mfma_f32_16x16x32_bf16(vw[w2][jd], pw[1][w2], xa[1][jd], 0,0,0);
      }
      lacc[0] = __builtin_amdgcn_mfma_f32_16x16x32_bf16(ones8, pw[0][w2], lacc[0], 0,0,0);
      lacc[1] = __builtin_amdgcn_mfma_f32_16x16x32_bf16(ones8, pw[1][w2], lacc[1], 0,0,0);
    }
    __builtin_amdgcn_s_setprio(0);

    cur = (cur==2) ? 0 : cur+1;
  }

  // write O: lane holds q=l16 (per group), d = jd*16 + 4*g16 + r
  #pragma unroll
  for (int qg=0;qg<2;qg++){
    const float rl = 1.f / lacc[qg][0];
    const size_t row = (size_t)(b*2048 + q0 + qg*16 + l16);
    #pragma unroll
    for (int jd=0;jd<4;jd++){
      bf16x4 ov = { f2b(xa[qg][jd][0]*rl), f2b(xa[qg][jd][1]*rl),
                    f2b(xa[qg][jd][2]*rl), f2b(xa[qg][jd][3]*rl) };
      *(bf16x4*)(O + row*1024 + h*64 + jd*16 + 4*g16) = ov;
    }
  }
}

// ---------------- residual + layernorm (row = 1024) ----------------
// X in bf16; residual R is f32 (RBF=0) or bf16 (RBF=1).
template<int RBF>
__global__ __launch_bounds__(256) void addln_kernel(
    const bf16* __restrict__ X, const void* __restrict__ R,
    const float* __restrict__ g, const float* __restrict__ be,
    float* __restrict__ of, bf16* __restrict__ ob)
{
  const int row = blockIdx.x, tid = threadIdx.x;
  const bf16x4 vxb = *(const bf16x4*)(X + (size_t)row*1024 + tid*4);
  float r0, r1, r2, r3;
  if constexpr (RBF==1){
    const bf16x4 vrb = *(const bf16x4*)((const bf16*)R + (size_t)row*1024 + tid*4);
    r0 = (float)vrb[0]; r1 = (float)vrb[1]; r2 = (float)vrb[2]; r3 = (float)vrb[3];
  } else {
    const float4 vr = ((const float4*)((const float*)R + (size_t)row*1024))[tid];
    r0 = vr.x; r1 = vr.y; r2 = vr.z; r3 = vr.w;
  }
  const float a0 = (float)vxb[0]+r0, a1 = (float)vxb[1]+r1;
  const float a2 = (float)vxb[2]+r2, a3 = (float)vxb[3]+r3;
  float s = a0+a1+a2+a3;
  float q = a0*a0 + a1*a1 + a2*a2 + a3*a3;
  #pragma unroll
  for (int off=1; off<64; off<<=1){
    s += __shfl_xor(s, off, 64);
    q += __shfl_xor(q, off, 64);
  }
  __shared__ float sb[8];
  if ((tid&63)==0){ sb[tid>>6] = s; sb[4+(tid>>6)] = q; }
  __syncthreads();
  s = sb[0]+sb[1]+sb[2]+sb[3];
  q = sb[4]+sb[5]+sb[6]+sb[7];
  const float mu = s*(1.f/1024.f);
  const float rs = rsqrtf(q*(1.f/1024.f) - mu*mu + 1e-5f);
  const float4 gg = ((const float4*)g)[tid];
  const float4 bb = ((const float4*)be)[tid];
  const float o0 = (a0-mu)*rs*gg.x + bb.x;
  const float o1 = (a1-mu)*rs*gg.y + bb.y;
  const float o2 = (a2-mu)*rs*gg.z + bb.z;
  const float o3 = (a3-mu)*rs*gg.w + bb.w;
  if (of){
    float4 o; o.x=o0; o.y=o1; o.z=o2; o.w=o3;
    ((float4*)(of + (size_t)row*1024))[tid] = o;
  }
  if (ob){
    bf16x4 u = { f2b(o0), f2b(o1), f2b(o2), f2b(o3) };
    *(bf16x4*)(ob + (size_t)row*1024 + tid*4) = u;
  }
}

// ---------------- launch ----------------
extern "C" void kernel_launch(void* const* d_in, const int* in_sizes, int n_in,
                              void* d_out, int out_size, void* d_ws, size_t ws_size,
                              hipStream_t stream)
{
  const float* src  = (const float*)d_in[0];
  const int*   mask = (const int*)  d_in[1];
  const float* Wq = (const float*)d_in[2];  const float* bq = (const float*)d_in[3];
  const float* Wk = (const float*)d_in[4];  const float* bk = (const float*)d_in[5];
  const float* Wv = (const float*)d_in[6];  const float* bv = (const float*)d_in[7];
  const float* Wo = (const float*)d_in[8];  const float* bo = (const float*)d_in[9];
  const float* W1 = (const float*)d_in[10]; const float* b1 = (const float*)d_in[11];
  const float* W2 = (const float*)d_in[12]; const float* b2 = (const float*)d_in[13];
  const float* g1 = (const float*)d_in[14]; const float* be1 = (const float*)d_in[15];
  const float* g2 = (const float*)d_in[16]; const float* be2 = (const float*)d_in[17];

  char* ws = (char*)d_ws;
  const size_t MB = 1u<<20;
  bf16* srcb  = (bf16*)(ws + 0*MB);    // 16 MB  [dead after QKV gemm]
  bf16* Wqkvt = (bf16*)(ws + 16*MB);   // 6 MB
  bf16* Wot   = (bf16*)(ws + 22*MB);   // 2 MB
  bf16* W1t   = (bf16*)(ws + 24*MB);   // 8 MB
  bf16* W2t   = (bf16*)(ws + 32*MB);   // 8 MB
  bf16* Qb    = (bf16*)(ws + 40*MB);   // 16 MB [dead after attn]
  bf16* Kb    = (bf16*)(ws + 56*MB);   // 16 MB [dead after attn]
  bf16* Vtb   = (bf16*)(ws + 72*MB);   // 16 MB [dead after attn]
  bf16* AO    = (bf16*)(ws + 88*MB);   // 16 MB [dead after O-proj]
  bf16*  X1   = (bf16*)(ws + 40*MB);   // 16 MB over Qb (bf16)
  bf16*  S1B  = (bf16*)(ws + 72*MB);   // 16 MB over Vtb (LN1 out, bf16 only)
  bf16*  H1   = (bf16*)(ws + 104*MB);  // 64 MB
  bf16*  F2   = (bf16*)(ws + 40*MB);   // 16 MB over X1 (dead after LN1)

  const float QSC = 0.18033688011112042f;   // 0.125 * log2(e)

  prep_kernel<<<20480, 256, 0, stream>>>(src, srcb, Wq, Wk, Wv, Wo, W1, W2,
                                         Wqkvt, Wot, W1t, W2t);

  // fused QKV projection (N=3072): wide-N -> plain bx-fastest order
  gemm_bt_kernel<4,0><<<24*64, 256, 0, stream>>>(
      srcb, Wqkvt, bq, Qb, 8192, 3072, 1024, QSC, bk, bv, Kb, Vtb);

  attn_kernel<<<512, 512, 0, stream>>>(Qb, Kb, Vtb, mask, AO);

  // O-proj (N=1024): narrow-N -> XCD row-panel ownership
  gemm_bt_kernel<1,1><<<8*64,  256, 0, stream>>>(
      AO, Wot, bo, X1, 8192, 1024, 1024, 1.f, nullptr, nullptr, nullptr, nullptr);
  // LN1: residual = src (f32); bf16 output only
  addln_kernel<0><<<8192, 256, 0, stream>>>(X1, src, g1, be1,
                                            (float*)nullptr, S1B);

  // FFN1 (N=4096, swish): wide-N -> plain order ; FFN2 (N=1024): XCD-remap
  gemm_bt_kernel<2,0><<<32*64, 256, 0, stream>>>(
      S1B, W1t, b1, H1, 8192, 4096, 1024, 1.f, nullptr, nullptr, nullptr, nullptr);
  gemm_bt_kernel<1,1><<<8*64,  256, 0, stream>>>(
      H1,  W2t, b2, F2, 8192, 1024, 4096, 1.f, nullptr, nullptr, nullptr, nullptr);
  // LN2: residual = S1B (bf16); f32 output to d_out
  addln_kernel<1><<<8192, 256, 0, stream>>>(F2, S1B, g2, be2,
                                            (float*)d_out, (bf16*)nullptr);
}

// Round 22
// 361.852 us; speedup vs baseline: 1.0798x; 1.0204x over previous
//
#include <hip/hip_runtime.h>
#include <stdint.h>

// EncoderLayer on MI355X (gfx950), bf16 MFMA pipeline.
// B=4, S=2048, HID=1024, HEADS=16, HD=64, PF=4096. M = B*S = 8192.

typedef __bf16 bf16;
typedef __bf16 bf16x4 __attribute__((ext_vector_type(4)));
typedef __bf16 bf16x8 __attribute__((ext_vector_type(8)));
typedef float  f32x4  __attribute__((ext_vector_type(4)));

__device__ __forceinline__ bf16 f2b(float x){
  uint32_t u = __builtin_bit_cast(uint32_t, x);
  uint32_t r = (u + 0x7FFFu + ((u >> 16) & 1u)) >> 16;   // RNE
  return __builtin_bit_cast(bf16, (uint16_t)r);
}

__device__ __forceinline__ float ex2(float x){
#if __has_builtin(__builtin_amdgcn_exp2f)
  return __builtin_amdgcn_exp2f(x);
#else
  return __exp2f(x);
#endif
}

// async global->LDS, 16B per lane (LDS dest = wave-uniform base + lane*16,
// global source is per-lane)
__device__ __forceinline__ void gload_lds16(const void* g, void* l){
  __builtin_amdgcn_global_load_lds(
      (const __attribute__((address_space(1))) void*)g,
      (__attribute__((address_space(3))) void*)l, 16, 0, 0);
}

// ---------------- prep: src cast + all 6 weight transposes, one launch ------
__global__ __launch_bounds__(256) void prep_kernel(
    const float* __restrict__ src, bf16* __restrict__ srcb,
    const float* __restrict__ Wq, const float* __restrict__ Wk,
    const float* __restrict__ Wv, const float* __restrict__ Wo,
    const float* __restrict__ W1, const float* __restrict__ W2,
    bf16* __restrict__ Wqkvt, bf16* __restrict__ Wot,
    bf16* __restrict__ W1t,  bf16* __restrict__ W2t)
{
  __shared__ float t[32][33];
  const int bb = blockIdx.x, tid = threadIdx.x;
  if (bb < 8192){
    const int i = bb*256 + tid;
    const float4 v = ((const float4*)src)[i];
    bf16x4 u = { f2b(v.x), f2b(v.y), f2b(v.z), f2b(v.w) };
    *(bf16x4*)(srcb + (size_t)i*4) = u;
    return;
  }
  const int idx = bb - 8192;
  const float* W; bf16* Wt; int K, N, bx, by;
  if (idx < 3072){
    const int r = idx >> 10, j = idx & 1023;
    W = (r==0)?Wq:(r==1)?Wk:Wv; Wt = Wqkvt + (size_t)r*1024*1024;
    K = 1024; N = 1024; bx = j & 31; by = j >> 5;
  } else if (idx < 4096){
    const int j = idx - 3072;
    W = Wo; Wt = Wot; K = 1024; N = 1024; bx = j & 31; by = j >> 5;
  } else if (idx < 8192){
    const int j = idx - 4096;
    W = W1; Wt = W1t; K = 1024; N = 4096; bx = j & 127; by = j >> 7;
  } else {
    const int j = idx - 8192;
    W = W2; Wt = W2t; K = 4096; N = 1024; bx = j & 31; by = j >> 5;
  }
  const int x = tid & 31, y = tid >> 5;
  const int n0 = bx*32, k0 = by*32;
  #pragma unroll
  for (int r=0;r<4;r++) t[y+8*r][x] = W[(size_t)(k0+y+8*r)*N + n0+x];
  __syncthreads();
  #pragma unroll
  for (int r=0;r<4;r++) Wt[(size_t)(n0+y+8*r)*K + k0+x] = f2b(t[x][y+8*r]);
}

// ---------------- GEMM 128x128, BK=64, 2-buf single-barrier pipeline --------
// C = A[M][K] * Bt[N][K]^T + bias. 4 waves (2x2), wave = 64x64 = 4x4 frags of
// 16x16x32. Reg-staged prefetch, TWO LDS buffers (64 KB -> 2 blocks/CU),
// ONE barrier per 64-K step. OMODE==4 V-region: epilogue routes the 128x128
// V^T tile through LDS (staging buffers, dead after the K-loop) so global
// stores are coalesced 256B runs instead of scattered 8B (same values, same
// addresses -> bit-identical).
template<int OMODE, int REMAP>
__global__ __launch_bounds__(256) void gemm_bt_kernel(
    const bf16* __restrict__ A, const bf16* __restrict__ Bt,
    const float* __restrict__ bias, void* __restrict__ C,
    int M, int N, int K, float oscale,
    const float* __restrict__ bias2, const float* __restrict__ bias3,
    void* __restrict__ C2, void* __restrict__ C3)
{
  __shared__ bf16 SMEM[32768];                 // 64 KB: As|Bs dbuf, V-tile reuse
  const int tid = threadIdx.x;
  const int w = tid >> 6, lane = tid & 63;
  const int wr = w >> 1, wc = w & 1;
  const int g16 = lane >> 4, l16 = lane & 15;

  const int nbx = N >> 7;
  const int nby = M >> 7;
  const int lin = blockIdx.x;
  int bx, by;
  if constexpr (REMAP==1){
    const int xcd = lin & 7;
    const int j   = lin >> 3;
    by = xcd * (nby >> 3) + (j / nbx);
    bx = j % nbx;
  } else {
    bx = lin % nbx;
    by = lin / nbx;
  }
  const int m0 = by*128, n0 = bx*128;

  const int srow  = tid >> 3;
  const int sslot = ((tid & 7) ^ (srow & 7)) * 8;
  const bf16* gA = A  + (size_t)(m0 + srow)*K + sslot;
  const bf16* gB = Bt + (size_t)(n0 + srow)*K + sslot;

  f32x4 acc[4][4];
  const f32x4 fz = {0.f,0.f,0.f,0.f};
  #pragma unroll
  for (int m=0;m<4;m++)
    #pragma unroll
    for (int n=0;n<4;n++) acc[m][n] = fz;

  bf16x8 ra[4], rb[4];
  #pragma unroll
  for (int k=0;k<4;k++){
    ra[k] = *(const bf16x8*)(gA + (size_t)(32*k)*K);
    rb[k] = *(const bf16x8*)(gB + (size_t)(32*k)*K);
  }
  asm volatile("s_waitcnt vmcnt(0)" ::: "memory");
  #pragma unroll
  for (int k=0;k<4;k++){
    *(bf16x8*)&SMEM[(tid + 256*k)*8] = ra[k];              // As buf0
    *(bf16x8*)&SMEM[16384 + (tid + 256*k)*8] = rb[k];      // Bs buf0
  }
  const int NT = K >> 6;
  if (NT > 1){
    #pragma unroll
    for (int k=0;k<4;k++){
      ra[k] = *(const bf16x8*)(gA + (size_t)(32*k)*K + 64);
      rb[k] = *(const bf16x8*)(gB + (size_t)(32*k)*K + 64);
    }
  }

  const int l7 = l16 & 7;
  for (int t = 0; t < NT; ++t){
    asm volatile("s_waitcnt lgkmcnt(0)" ::: "memory");
    __builtin_amdgcn_s_barrier();
    asm volatile("" ::: "memory");

    const bf16* as = &SMEM[(t&1)*8192];
    const bf16* bs = &SMEM[16384 + (t&1)*8192];
    bf16x8 af[2][4], bfv[2][4];
    #pragma unroll
    for (int kk=0;kk<2;kk++){
      #pragma unroll
      for (int m=0;m<4;m++){
        const int r = wr*64 + m*16 + l16;
        af[kk][m] = *(const bf16x8*)&as[r*64 + ((((kk<<2)+g16) ^ l7)<<3)];
      }
      #pragma unroll
      for (int n=0;n<4;n++){
        const int r = wc*64 + n*16 + l16;
        bfv[kk][n] = *(const bf16x8*)&bs[r*64 + ((((kk<<2)+g16) ^ l7)<<3)];
      }
    }
    if (t+1 < NT){
      asm volatile("s_waitcnt vmcnt(0)" ::: "memory");
      bf16* aw = &SMEM[((t+1)&1)*8192];
      bf16* bw = &SMEM[16384 + ((t+1)&1)*8192];
      #pragma unroll
      for (int k=0;k<4;k++){
        *(bf16x8*)&aw[(tid + 256*k)*8] = ra[k];
        *(bf16x8*)&bw[(tid + 256*k)*8] = rb[k];
      }
      if (t+2 < NT){
        #pragma unroll
        for (int k=0;k<4;k++){
          ra[k] = *(const bf16x8*)(gA + (size_t)(32*k)*K + (t+2)*64);
          rb[k] = *(const bf16x8*)(gB + (size_t)(32*k)*K + (t+2)*64);
        }
      }
    }
    #pragma unroll
    for (int kk=0;kk<2;kk++)
      #pragma unroll
      for (int m=0;m<4;m++)
        #pragma unroll
        for (int n=0;n<4;n++)
          acc[m][n] = __builtin_amdgcn_mfma_f32_16x16x32_bf16(
              af[kk][m], bfv[kk][n], acc[m][n], 0, 0, 0);
  }

  // epilogue: D[i][j]: j = lane&15, i = 4*(lane>>4)+reg  [measured layout]
  const int cb = n0 + wc*64 + l16;
  if constexpr (OMODE==4){
    const int region = n0 >> 10;
    const float* bs2 = (region==0)? bias : (region==1)? bias2 : bias3;
    const int colbase = region << 10;
    if (region==2){
      // ---- V: transpose through LDS, then coalesced global stores ----
      // vt[cl_local][132] bf16 (264B row stride: ~2-way banks both phases)
      asm volatile("s_waitcnt lgkmcnt(0)" ::: "memory");
      __builtin_amdgcn_s_barrier();              // all waves done with As/Bs
      asm volatile("" ::: "memory");
      bf16* vt = SMEM;                           // 128*132 = 16896 elems
      #pragma unroll
      for (int n=0;n<4;n++){
        const int cl = cb + n*16 - colbase;      // global d
        const int cll = wc*64 + n*16 + l16;      // cl within block (0..127)
        const float bv = bs2[cl];
        #pragma unroll
        for (int m=0;m<4;m++){
          // s_local = wr*64 + m*16 + g16*4 + r ; tile = wr ; s6b = m*16+g16*4
          const int s6b = m*16 + g16*4;
          const int spb = (s6b & 32) | ((s6b & 12) << 1) | ((s6b & 16) >> 2);
          bf16x4 v4 = { f2b(acc[m][n][0] + bv), f2b(acc[m][n][1] + bv),
                        f2b(acc[m][n][2] + bv), f2b(acc[m][n][3] + bv) };
          *(bf16x4*)&vt[cll*132 + wr*64 + spb] = v4;
        }
      }
      asm volatile("s_waitcnt lgkmcnt(0)" ::: "memory");
      __builtin_amdgcn_s_barrier();              // vt complete
      asm volatile("" ::: "memory");
      const size_t bq = (size_t)m0 >> 11;
      const int scol0 = m0 & 2047;
      bf16* Vout = (bf16*)C3;
      #pragma unroll
      for (int i=0;i<8;i++){
        const int idx = tid + 256*i;             // 2048 chunks of 16B
        const int cll = idx >> 4, ch = idx & 15;
        const bf16x8 v8 = *(const bf16x8*)&vt[cll*132 + ch*8];
        const int dg = (n0 - 2048) + cll;
        *(bf16x8*)&Vout[(bq*1024 + (size_t)dg)*2048 + scol0 + ch*8] = v8;
      }
    } else {
      #pragma unroll
      for (int n=0;n<4;n++){
        const int cl = cb + n*16 - colbase;
        const float bv = bs2[cl];
        #pragma unroll
        for (int m=0;m<4;m++){
          const int rbase = m0 + wr*64 + m*16 + g16*4;
          #pragma unroll
          for (int r=0;r<4;r++){
            const float v = acc[m][n][r] + bv;
            const size_t row = (size_t)(rbase + r);
            if (region==0) ((bf16*)C )[row*1024 + cl] = f2b(v * oscale);
            else           ((bf16*)C2)[row*1024 + cl] = f2b(v);
          }
        }
      }
    }
  } else {
    #pragma unroll
    for (int n=0;n<4;n++){
      const int col = cb + n*16;
      const float bv = bias[col];
      #pragma unroll
      for (int m=0;m<4;m++){
        const int rbase = m0 + wr*64 + m*16 + g16*4;
        #pragma unroll
        for (int r=0;r<4;r++){
          float v = acc[m][n][r] + bv;
          const size_t row = (size_t)(rbase + r);
          if constexpr (OMODE==0){
            ((float*)C)[row*N + col] = v;
          } else if constexpr (OMODE==1){
            ((bf16*)C)[row*N + col] = f2b(v * oscale);
          } else {
            v = v / (1.f + __expf(-v));
            ((bf16*)C)[row*N + col] = f2b(v);
          }
        }
      }
    }
  }
}

// ---------------- flash attention (depth-2 staging, drift-compute) ---------
// grid 512 blocks, XCD-aware (b,h) clustering. 8 waves/block (512 thr),
// wave = 32 q. KV tile 64, THREE LDS bufs (49KB -> 2 blocks/CU).
// Per tile: ds_read buf[t%3] -> stage(t+2) -> vmcnt(2) -> lgkmcnt(0)
// -> raw s_barrier -> compute (no trailing barrier: waves drift).
// - PV at K=32 via kv->k relabeling; V^T pre-interleaved in global memory.
// - l = sum(P) via MFMAs with A=ones.  - No running max (exp2-domain, safe).
__global__ __launch_bounds__(512) void attn_kernel(
    const bf16* __restrict__ Q, const bf16* __restrict__ Km,
    const bf16* __restrict__ Vt, const int* __restrict__ msk,
    bf16* __restrict__ O)
{
  __shared__ bf16 Ks[3][64*64];
  __shared__ bf16 Vs[3][64*64];
  __shared__ int  Mflag[32];

  const int tid = threadIdx.x;
  const int w = tid>>6, lane = tid&63;          // w = 0..7
  const int g16 = lane>>4, l16 = lane&15;
  const int lin = blockIdx.x;                   // 0..511
  const int xcd = lin & 7, idx = lin >> 3;      // XCD = blockIdx % 8
  const int bh  = xcd*8 + (idx >> 3);           // 8 (b,h) groups per XCD
  const int qt  = idx & 7;                      // 8 q-tiles of 256
  const int b = bh >> 4, h = bh & 15;
  const int q0 = qt*256 + w*32;

  const bf16* Kb = Km + (size_t)b*2048*1024 + h*64;
  const bf16* Vb = Vt + (size_t)(b*16 + h)*64*2048;
  const int*  mb = msk + b*2048;

  if (tid < 32) Mflag[tid] = 1;

  const int srow = w*8 + (lane>>3);
  const int sslot = ((lane&7) ^ (lane>>3)) * 8;
  const bf16* gK0 = Kb + (size_t)srow*1024 + sslot;
  const bf16* gV0 = Vb + (size_t)srow*2048 + sslot;

  auto stage = [&](int buf, int kv0){
    gload_lds16(gK0 + (size_t)kv0*1024, &Ks[buf][w*512]);
    gload_lds16(gV0 + kv0,              &Vs[buf][w*512]);
  };

  // Q fragments (B-operand): col=q=l16, k=d=g16*8+e (+32)
  bf16x8 qf[2][2];
  #pragma unroll
  for (int qg=0;qg<2;qg++){
    const bf16* qp = Q + (size_t)(b*2048 + q0 + qg*16 + l16)*1024 + h*64 + g16*8;
    qf[qg][0] = *(const bf16x8*)qp;
    qf[qg][1] = *(const bf16x8*)(qp + 32);
  }

  __syncthreads();                       // Mflag init visible
  {
    const int4 a = *(const int4*)(mb + tid*4);
    const bool ok = a.x && a.y && a.z && a.w;
    if (!ok) atomicAnd(&Mflag[tid>>4], 0);
  }
  stage(0, 0);
  stage(1, 64);
  __syncthreads();                       // flags final + stage(0),(1) landed

  const int l7 = l16 & 7;
  const int kOff0 = l16*64 + ((g16     ^ l7) << 3);   // also V slot w2=0
  const int kOff1 = l16*64 + (((4+g16) ^ l7) << 3);   // also V slot w2=1

  bf16x8 ones8;
  #pragma unroll
  for (int j=0;j<8;j++) ones8[j] = (bf16)1.0f;

  const f32x4 fz = {0.f,0.f,0.f,0.f};
  f32x4 xa[2][4];
  f32x4 lacc[2] = {fz, fz};
  #pragma unroll
  for (int qg=0;qg<2;qg++)
    #pragma unroll
    for (int jd=0;jd<4;jd++) xa[qg][jd] = fz;

  int cur = 0;
  for (int it = 0; it < 32; ++it){
    const int kv0 = it*64;
    const bf16* ksb = &Ks[cur][0];
    const bf16* vsb = &Vs[cur][0];

    bf16x8 kk[4][2];
    #pragma unroll
    for (int t=0;t<4;t++){
      kk[t][0] = *(const bf16x8*)(ksb + t*1024 + kOff0);
      kk[t][1] = *(const bf16x8*)(ksb + t*1024 + kOff1);
    }
    bf16x8 vw[2][4];
    #pragma unroll
    for (int jd=0;jd<4;jd++){
      vw[0][jd] = *(const bf16x8*)(vsb + jd*1024 + kOff0);
      vw[1][jd] = *(const bf16x8*)(vsb + jd*1024 + kOff1);
    }

    if (it < 30){
      const int pb = (cur >= 1) ? cur-1 : 2;
      stage(pb, kv0 + 128);
    }
    if (it < 30)       asm volatile("s_waitcnt vmcnt(2)" ::: "memory");
    else if (it == 30) asm volatile("s_waitcnt vmcnt(0)" ::: "memory");
    asm volatile("s_waitcnt lgkmcnt(0)" ::: "memory");   // reads consumed
    if (it < 31){
      asm volatile("" ::: "memory");
      __builtin_amdgcn_s_barrier();
      asm volatile("" ::: "memory");
    }

    // ---- compute tile it (no trailing barrier: waves drift) ----
    f32x4 st[2][4];
    __builtin_amdgcn_s_setprio(1);
    #pragma unroll
    for (int qg=0;qg<2;qg++){
      #pragma unroll
      for (int t=0;t<4;t++){
        f32x4 a = fz;
        a = __builtin_amdgcn_mfma_f32_16x16x32_bf16(kk[t][0], qf[qg][0], a, 0,0,0);
        a = __builtin_amdgcn_mfma_f32_16x16x32_bf16(kk[t][1], qf[qg][1], a, 0,0,0);
        st[qg][t] = a;
      }
    }
    __builtin_amdgcn_s_setprio(0);

    if (!Mflag[it]){
      int4 mm[4];
      #pragma unroll
      for (int t=0;t<4;t++) mm[t] = *(const int4*)(mb + kv0 + t*16 + 4*g16);
      #pragma unroll
      for (int qg=0;qg<2;qg++)
        #pragma unroll
        for (int t=0;t<4;t++){
          st[qg][t][0] = (mm[t].x==0) ? -1e9f : st[qg][t][0];
          st[qg][t][1] = (mm[t].y==0) ? -1e9f : st[qg][t][1];
          st[qg][t][2] = (mm[t].z==0) ? -1e9f : st[qg][t][2];
          st[qg][t][3] = (mm[t].w==0) ? -1e9f : st[qg][t][3];
        }
    }

    bf16x8 pw[2][2];
    #pragma unroll
    for (int qg=0;qg<2;qg++){
      #pragma unroll
      for (int t=0;t<4;t++){
        const int hb = (t&1)*4;
        pw[qg][t>>1][hb+0] = (bf16)ex2(st[qg][t][0]);
        pw[qg][t>>1][hb+1] = (bf16)ex2(st[qg][t][1]);
        pw[qg][t>>1][hb+2] = (bf16)ex2(st[qg][t][2]);
        pw[qg][t>>1][hb+3] = (bf16)ex2(st[qg][t][3]);
      }
    }
    __builtin_amdgcn_s_setprio(1);
    #pragma unroll
    for (int w2=0;w2<2;w2++){
      #pragma unroll
      for (int jd=0;jd<4;jd++){
        xa[0][jd] = __builtin_amdgcn_mfma_f32_16x16x32_bf16(vw[w2][jd], pw[0][w2], xa[0][jd], 0,0,0);
        xa[1][jd] = __builtin_amdgcn_mfma_f32_16x16x32_bf16(vw[w2][jd], pw[1][w2], xa[1][jd], 0,0,0);
      }
      lacc[0] = __builtin_amdgcn_mfma_f32_16x16x32_bf16(ones8, pw[0][w2], lacc[0], 0,0,0);
      lacc[1] = __builtin_amdgcn_mfma_f32_16x16x32_bf16(ones8, pw[1][w2], lacc[1], 0,0,0);
    }
    __builtin_amdgcn_s_setprio(0);

    cur = (cur==2) ? 0 : cur+1;
  }

  // write O: lane holds q=l16 (per group), d = jd*16 + 4*g16 + r
  #pragma unroll
  for (int qg=0;qg<2;qg++){
    const float rl = 1.f / lacc[qg][0];
    const size_t row = (size_t)(b*2048 + q0 + qg*16 + l16);
    #pragma unroll
    for (int jd=0;jd<4;jd++){
      bf16x4 ov = { f2b(xa[qg][jd][0]*rl), f2b(xa[qg][jd][1]*rl),
                    f2b(xa[qg][jd][2]*rl), f2b(xa[qg][jd][3]*rl) };
      *(bf16x4*)(O + row*1024 + h*64 + jd*16 + 4*g16) = ov;
    }
  }
}

// ---------------- residual + layernorm (row = 1024) ----------------
// X in bf16; residual R is f32 (RBF=0) or bf16 (RBF=1).
template<int RBF>
__global__ __launch_bounds__(256) void addln_kernel(
    const bf16* __restrict__ X, const void* __restrict__ R,
    const float* __restrict__ g, const float* __restrict__ be,
    float* __restrict__ of, bf16* __restrict__ ob)
{
  const int row = blockIdx.x, tid = threadIdx.x;
  const bf16x4 vxb = *(const bf16x4*)(X + (size_t)row*1024 + tid*4);
  float r0, r1, r2, r3;
  if constexpr (RBF==1){
    const bf16x4 vrb = *(const bf16x4*)((const bf16*)R + (size_t)row*1024 + tid*4);
    r0 = (float)vrb[0]; r1 = (float)vrb[1]; r2 = (float)vrb[2]; r3 = (float)vrb[3];
  } else {
    const float4 vr = ((const float4*)((const float*)R + (size_t)row*1024))[tid];
    r0 = vr.x; r1 = vr.y; r2 = vr.z; r3 = vr.w;
  }
  const float a0 = (float)vxb[0]+r0, a1 = (float)vxb[1]+r1;
  const float a2 = (float)vxb[2]+r2, a3 = (float)vxb[3]+r3;
  float s = a0+a1+a2+a3;
  float q = a0*a0 + a1*a1 + a2*a2 + a3*a3;
  #pragma unroll
  for (int off=1; off<64; off<<=1){
    s += __shfl_xor(s, off, 64);
    q += __shfl_xor(q, off, 64);
  }
  __shared__ float sb[8];
  if ((tid&63)==0){ sb[tid>>6] = s; sb[4+(tid>>6)] = q; }
  __syncthreads();
  s = sb[0]+sb[1]+sb[2]+sb[3];
  q = sb[4]+sb[5]+sb[6]+sb[7];
  const float mu = s*(1.f/1024.f);
  const float rs = rsqrtf(q*(1.f/1024.f) - mu*mu + 1e-5f);
  const float4 gg = ((const float4*)g)[tid];
  const float4 bb = ((const float4*)be)[tid];
  const float o0 = (a0-mu)*rs*gg.x + bb.x;
  const float o1 = (a1-mu)*rs*gg.y + bb.y;
  const float o2 = (a2-mu)*rs*gg.z + bb.z;
  const float o3 = (a3-mu)*rs*gg.w + bb.w;
  if (of){
    float4 o; o.x=o0; o.y=o1; o.z=o2; o.w=o3;
    ((float4*)(of + (size_t)row*1024))[tid] = o;
  }
  if (ob){
    bf16x4 u = { f2b(o0), f2b(o1), f2b(o2), f2b(o3) };
    *(bf16x4*)(ob + (size_t)row*1024 + tid*4) = u;
  }
}

// ---------------- launch ----------------
extern "C" void kernel_launch(void* const* d_in, const int* in_sizes, int n_in,
                              void* d_out, int out_size, void* d_ws, size_t ws_size,
                              hipStream_t stream)
{
  const float* src  = (const float*)d_in[0];
  const int*   mask = (const int*)  d_in[1];
  const float* Wq = (const float*)d_in[2];  const float* bq = (const float*)d_in[3];
  const float* Wk = (const float*)d_in[4];  const float* bk = (const float*)d_in[5];
  const float* Wv = (const float*)d_in[6];  const float* bv = (const float*)d_in[7];
  const float* Wo = (const float*)d_in[8];  const float* bo = (const float*)d_in[9];
  const float* W1 = (const float*)d_in[10]; const float* b1 = (const float*)d_in[11];
  const float* W2 = (const float*)d_in[12]; const float* b2 = (const float*)d_in[13];
  const float* g1 = (const float*)d_in[14]; const float* be1 = (const float*)d_in[15];
  const float* g2 = (const float*)d_in[16]; const float* be2 = (const float*)d_in[17];

  char* ws = (char*)d_ws;
  const size_t MB = 1u<<20;
  bf16* srcb  = (bf16*)(ws + 0*MB);    // 16 MB  [dead after QKV gemm]
  bf16* Wqkvt = (bf16*)(ws + 16*MB);   // 6 MB
  bf16* Wot   = (bf16*)(ws + 22*MB);   // 2 MB
  bf16* W1t   = (bf16*)(ws + 24*MB);   // 8 MB
  bf16* W2t   = (bf16*)(ws + 32*MB);   // 8 MB
  bf16* Qb    = (bf16*)(ws + 40*MB);   // 16 MB [dead after attn]
  bf16* Kb    = (bf16*)(ws + 56*MB);   // 16 MB [dead after attn]
  bf16* Vtb   = (bf16*)(ws + 72*MB);   // 16 MB [dead after attn]
  bf16* AO    = (bf16*)(ws + 88*MB);   // 16 MB [dead after O-proj]
  bf16*  X1   = (bf16*)(ws + 40*MB);   // 16 MB over Qb (bf16)
  bf16*  S1B  = (bf16*)(ws + 72*MB);   // 16 MB over Vtb (LN1 out, bf16 only)
  bf16*  H1   = (bf16*)(ws + 104*MB);  // 64 MB
  bf16*  F2   = (bf16*)(ws + 40*MB);   // 16 MB over X1 (dead after LN1)

  const float QSC = 0.18033688011112042f;   // 0.125 * log2(e)

  prep_kernel<<<20480, 256, 0, stream>>>(src, srcb, Wq, Wk, Wv, Wo, W1, W2,
                                         Wqkvt, Wot, W1t, W2t);

  // fused QKV projection (N=3072): wide-N -> plain bx-fastest order
  gemm_bt_kernel<4,0><<<24*64, 256, 0, stream>>>(
      srcb, Wqkvt, bq, Qb, 8192, 3072, 1024, QSC, bk, bv, Kb, Vtb);

  attn_kernel<<<512, 512, 0, stream>>>(Qb, Kb, Vtb, mask, AO);

  // O-proj (N=1024): narrow-N -> XCD row-panel ownership
  gemm_bt_kernel<1,1><<<8*64,  256, 0, stream>>>(
      AO, Wot, bo, X1, 8192, 1024, 1024, 1.f, nullptr, nullptr, nullptr, nullptr);
  // LN1: residual = src (f32); bf16 output only
  addln_kernel<0><<<8192, 256, 0, stream>>>(X1, src, g1, be1,
                                            (float*)nullptr, S1B);

  // FFN1 (N=4096, swish): wide-N -> plain order ; FFN2 (N=1024): XCD-remap
  gemm_bt_kernel<2,0><<<32*64, 256, 0, stream>>>(
      S1B, W1t, b1, H1, 8192, 4096, 1024, 1.f, nullptr, nullptr, nullptr, nullptr);
  gemm_bt_kernel<1,1><<<8*64,  256, 0, stream>>>(
      H1,  W2t, b2, F2, 8192, 1024, 4096, 1.f, nullptr, nullptr, nullptr, nullptr);
  // LN2: residual = S1B (bf16); f32 output to d_out
  addln_kernel<1><<<8192, 256, 0, stream>>>(F2, S1B, g2, be2,
                                            (float*)d_out, (bf16*)nullptr);
}